// Round 8
// baseline (144.191 us; speedup 1.0000x reference)
//
#include <hip/hip_runtime.h>

#define T_N 1024
#define B_N 512
#define HID 20
#define TB3 (T_N * B_N * 3)   // 1572864
#define MEPAD 1152            // me + 128 zero-pad (kl[d<=0] = 0)

typedef float f4v __attribute__((ext_vector_type(4), aligned(4)));

__device__ __forceinline__ float bcast_lane(float v, int l) {
    return __int_as_float(__builtin_amdgcn_readlane(__float_as_int(v), l));
}

// r0-proven LDS flag handshake (workgroup scope, acquire/release).
__device__ __forceinline__ void flag_set(int* f, int v) {
    if ((threadIdx.x & 63) == 0)
        __hip_atomic_store(f, v, __ATOMIC_RELEASE, __HIP_MEMORY_SCOPE_WORKGROUP);
}
__device__ __forceinline__ void flag_wait(int* f, int target) {
    while (__hip_atomic_load(f, __ATOMIC_ACQUIRE, __HIP_MEMORY_SCOPE_WORKGROUP) < target)
        __builtin_amdgcn_s_sleep(2);
}

// ---------------- Kernel 1: memory MLP, LDS-staged weights (r6 proven) ----------------
__global__ __launch_bounds__(64) void me_mlp_kernel(
    const float* __restrict__ t,
    const float* __restrict__ w1, const float* __restrict__ b1,
    const float* __restrict__ w2, const float* __restrict__ b2,
    const float* __restrict__ w3, const float* __restrict__ b3,
    const float* __restrict__ w4, const float* __restrict__ b4,
    float* __restrict__ me)
{
    __shared__ float sw2[HID * HID], sw3[HID * HID];
    __shared__ float sw1[HID], sb1[HID], sb2[HID], sb3[HID], sw4[HID];
    __shared__ float sb4;
    const int tx = threadIdx.x;

    for (int i = tx; i < HID * HID; i += 64) { sw2[i] = w2[i]; sw3[i] = w3[i]; }
    for (int i = tx; i < HID; i += 64) {
        sw1[i] = w1[i]; sb1[i] = b1[i]; sb2[i] = b2[i];
        sb3[i] = b3[i]; sw4[i] = w4[i];
    }
    if (tx == 0) sb4 = b4[0];
    __syncthreads();

    const int r = blockIdx.x * 64 + tx;
    if (r >= MEPAD) return;
    if (r >= T_N) { me[r] = 0.0f; return; }

    const float x = t[r];
    float h1[HID], h2[HID], h3[HID];
    #pragma unroll
    for (int k = 0; k < HID; ++k) h1[k] = tanhf(fmaf(x, sw1[k], sb1[k]));
    for (int j = 0; j < HID; ++j) {
        float s = sb2[j];
        #pragma unroll
        for (int k = 0; k < HID; ++k) s = fmaf(h1[k], sw2[k * HID + j], s);
        h2[j] = tanhf(s);
    }
    for (int j = 0; j < HID; ++j) {
        float s = sb3[j];
        #pragma unroll
        for (int k = 0; k < HID; ++k) s = fmaf(h2[k], sw3[k * HID + j], s);
        h3[j] = tanhf(s);
    }
    float o = sb4;
    #pragma unroll
    for (int k = 0; k < HID; ++k) o = fmaf(h3[k], sw4[k], o);
    me[r] = 1.0f / (1.0f + expf(-o));
}

// One helper conv bb-iteration: conv(source chunk at i0 -> target row Jt),
// accumulated into hm0..hm3. Identical numerics/order to the r0 inner loop.
#define CONV_BB(i0v, JTv)                                                   \
    {                                                                       \
        const int i0_ = (i0v);                                              \
        const float ihv = Ih[i0_ + lane];                                   \
        const float* gk = me + (T_N - ((JTv) - i0_) - lane);                \
        f4v L[16];                                                          \
        _Pragma("unroll")                                                   \
        for (int u = 0; u < 16; ++u) L[u] = *(const f4v*)(gk + 4 * u);      \
        _Pragma("unroll")                                                   \
        for (int g = 0; g < 8; ++g) {                                       \
            const float r0 = bcast_lane(ihv, 8 * g + 0);                    \
            const float r1 = bcast_lane(ihv, 8 * g + 1);                    \
            const float r2 = bcast_lane(ihv, 8 * g + 2);                    \
            const float r3 = bcast_lane(ihv, 8 * g + 3);                    \
            const float r4 = bcast_lane(ihv, 8 * g + 4);                    \
            const float r5 = bcast_lane(ihv, 8 * g + 5);                    \
            const float r6 = bcast_lane(ihv, 8 * g + 6);                    \
            const float r7 = bcast_lane(ihv, 8 * g + 7);                    \
            const f4v La = L[2 * g], Lb = L[2 * g + 1];                     \
            hm0 = fmaf(r0, La.x, hm0);                                      \
            hm1 = fmaf(r1, La.y, hm1);                                      \
            hm2 = fmaf(r2, La.z, hm2);                                      \
            hm3 = fmaf(r3, La.w, hm3);                                      \
            hm0 = fmaf(r4, Lb.x, hm0);                                      \
            hm1 = fmaf(r5, Lb.y, hm1);                                      \
            hm2 = fmaf(r6, Lb.z, hm2);                                      \
            hm3 = fmaf(r7, Lb.w, hm3);                                      \
        }                                                                   \
    }

// Compute pair (source bb -> target c), accumulate into Hs[c][w].
#define DO_PAIR(qv)                                                         \
    {                                                                       \
        const int bb_ = (qv) >> 4, c_ = (qv) & 15;                          \
        float hm0 = 0.f, hm1 = 0.f, hm2 = 0.f, hm3 = 0.f;                   \
        CONV_BB(bb_ * 64, c_ * 64);                                         \
        Hs[c_][w][lane] += (hm0 + hm1) + (hm2 + hm3);                       \
    }

// ---- STATIC EDF SCHEDULE (computed offline, deadline-verified) ----
// Pair byte = bb*16 + c. Ownership boustrophedon (bb%6 zigzag): w0 owns
// bb{0,5,6,11,12}, w1 {1,4,7,10,13}, w2 {2,3,8,9}. Release(bb,c)=iter bb+1,
// deadline=iter c-1 (before flagH publish). Per iteration: <=1 mandatory
// (deadline==today, always bb=p-1) + <=3 total. Per-(wave,target) order is
// ascending bb (matches r0's summation order).
static __device__ const unsigned char PTAB0[36] = {
 0x02,0x03,0x04, 0x05,0x06,0x07, 0x08,0x09,0x0A, 0x0B,0x0C,0x0D,
 0x0E,0x0F, 0x57,0x58,0x59, 0x68,0x5A,0x69, 0x6A,0x5B,0x6B,
 0x5C,0x6C,0x5D, 0x6D,0x5E,0x6E, 0x5F,0x6F, 0xBD,0xBE,0xBF, 0xCE,0xCF };
static __device__ const unsigned char PTAB1[35] = {
 0x13,0x14,0x15, 0x16,0x17,0x18, 0x19,0x1A,0x1B, 0x46,0x47,0x48,
 0x49,0x4A,0x4B, 0x1C,0x4C,0x1D, 0x79,0x7A,0x7B, 0x7C,0x4D,0x7D,
 0x1E,0x4E,0x7E, 0xAC,0xAD,0x1F, 0xAE,0x4F,0x7F, 0xAF, 0xDF };
static __device__ const unsigned char PTAB2[34] = {
 0x24,0x25,0x26, 0x35,0x36,0x27, 0x37,0x28,0x38, 0x29,0x39,0x2A,
 0x3A,0x2B,0x3B, 0x2C,0x3C,0x2D, 0x8A,0x8B,0x8C, 0x9B,0x9C,0x3D,
 0x8D,0x9D,0x2E, 0x3E,0x8E,0x9E, 0x2F,0x3F,0x8F, 0x9F };
static __device__ const unsigned char NTOT0[16] = {0,3,3,3,3,2,3,3,3,3,3,2,3,2,0,0};
static __device__ const unsigned char NMAN0[16] = {0,1,0,0,0,0,1,1,0,0,0,0,1,1,0,0};
static __device__ const unsigned char NTOT1[16] = {0,0,3,3,3,3,3,3,3,3,3,3,3,1,1,0};
static __device__ const unsigned char NMAN1[16] = {0,0,1,0,0,1,0,0,1,0,0,1,0,0,1,0};
static __device__ const unsigned char NTOT2[16] = {0,0,0,3,3,3,3,3,3,3,3,3,3,3,1,0};
static __device__ const unsigned char NMAN2[16] = {0,0,0,1,1,0,0,0,0,1,1,0,0,0,1,0};

// ---------------- Kernel 2: barrier-free producer/consumer pipeline ----------------
// Round-8: static-EDF smoothing of the helper convolution (r7's idea minus
// the runtime scheduler). Per helper iteration: prefetch table entries ->
// wait flagI -> <=1 MANDATORY pair -> publish flagH -> stores -> <=3
// work-ahead pairs. Partials accumulate incrementally in Hs[16][3][64];
// every target is final before its publish (offline-verified deadlines).
// Removes r6's late-iteration 5-bb Old bursts (the helper saturation that
// ate half of r6's predicted win).
__global__ __launch_bounds__(256, 2) void ode_kernel(
    const float* __restrict__ t,
    const float* __restrict__ y,
    const float* __restrict__ me,
    const float* __restrict__ betap,
    const float* __restrict__ gammap,
    float* __restrict__ out)
{
    const int b    = blockIdx.x;
    const int tx   = threadIdx.x;
    const int lane = tx & 63;
    const int wv   = tx >> 6;

    __shared__ float Ih[T_N];         // I trajectory
    __shared__ float Sh[T_N];         // S trajectory
    __shared__ float Hs[16][3][64];   // per-target helper partials (final before deadline)
    __shared__ int   flagI;           // serial -> helpers: chunks published
    __shared__ int   flagH[4];        // helpers -> serial: targets <= value finalized

    const float dt  = t[0] - t[1];   // 1/1024, exact
    const float rdt = 1.0f / dt;
    const float bet = betap[0];
    const float gam = gammap[0];
    const float Af  = dt * bet;
    const float Bf  = 1.0f - dt * gam;
    const float D2  = dt * dt;
    const float kl1 = me[T_N - 1];   // kl[1]

    float S = y[3 * b + 0];
    float I = y[3 * b + 1];
    const float Rc = S + I + y[3 * b + 2];

    for (int i = tx; i < 16 * 3 * 64; i += 256) ((float*)Hs)[i] = 0.f;
    if (tx == 0) { Ih[0] = I; Sh[0] = S; flagI = 0; flagH[1] = flagH[2] = flagH[3] = 0; }
    if (tx < 3) {
        out[3 * b + tx] = y[3 * b + tx];                        // solution row 0
        out[TB3 + (size_t)1023 * B_N * 3 + 3 * b + tx] = 0.0f;  // diff row 1023
    }
    __syncthreads();   // one-time init barrier (nothing in flight)

    if (wv == 0) {
        // ================= SERIAL WAVE (r0-proven; Hs now 16-deep) =================
        float W2 = 0.0f;
        for (int p = 0; p < 16; ++p) {
            const int Js = p * 64;
            if (p) {
                flag_wait(&flagH[1], p);
                flag_wait(&flagH[2], p);
                flag_wait(&flagH[3], p);
            }
            float W = W2 + (Hs[p][0][lane] + Hs[p][1][lane] + Hs[p][2][lane]);
            W2 = 0.0f;

            const float* gk  = me + (T_N - lane);        // kl[lane-q]
            const float* gk2 = me + (T_N - 64 - lane);   // kl[64+lane-q]
            f4v L[16], L2[16];
            #pragma unroll
            for (int u = 0; u < 16; ++u) {
                L[u]  = *(const f4v*)(gk  + 4 * u);
                L2[u] = *(const f4v*)(gk2 + 4 * u);
            }

            float mS = S, mI = I;
            float pre = bcast_lane(W, 0);

            {   // step 0 (chunk 0: initial condition)
                const float A0 = p ? Af : 0.0f;
                const float B0 = p ? Bf : 1.0f;
                const float D0 = p ? D2 : 0.0f;
                const float tot = pre;
                pre = bcast_lane(W, 1);
                const float SI = S * I;
                const float tI = B0 * I;
                const float u1 = fmaf(-A0, SI, S);
                I = fmaf(A0, SI, tI);
                S = fmaf(D0, tot, u1);
                if (lane == 0) { mS = S; mI = I; }
                W  = fmaf(L[0].x,  I, W);
                W2 = fmaf(L2[0].x, I, W2);
            }

#define BSTEP(c, KV, KV2)                                                 \
            {                                                             \
                const float tot = fmaf(kl1, I, pre);                      \
                pre = bcast_lane(W, ((c) + 1) & 63);                      \
                const float SI = S * I;                                   \
                const float tI = Bf * I;                                  \
                const float u1 = fmaf(-Af, SI, S);                        \
                I = fmaf(Af, SI, tI);                                     \
                S = fmaf(D2, tot, u1);                                    \
                if (lane == (c)) { mS = S; mI = I; }                      \
                W  = fmaf((KV),  I, W);                                   \
                W2 = fmaf((KV2), I, W2);                                  \
            }
#define BGRP(U)                                                           \
            BSTEP(4*(U)+0, L[U].x, L2[U].x)                               \
            BSTEP(4*(U)+1, L[U].y, L2[U].y)                               \
            BSTEP(4*(U)+2, L[U].z, L2[U].z)                               \
            BSTEP(4*(U)+3, L[U].w, L2[U].w)

            BSTEP(1, L[0].y, L2[0].y)
            BSTEP(2, L[0].z, L2[0].z)
            BSTEP(3, L[0].w, L2[0].w)
            BGRP(1)  BGRP(2)  BGRP(3)  BGRP(4)  BGRP(5)
            BGRP(6)  BGRP(7)  BGRP(8)  BGRP(9)  BGRP(10)
            BGRP(11) BGRP(12) BGRP(13) BGRP(14) BGRP(15)
#undef BGRP
#undef BSTEP

            Ih[Js + lane] = mI;
            Sh[Js + lane] = mS;
            flag_set(&flagI, p + 1);   // release: publishes Ih/Sh chunk p
        }
    } else {
        // ================= HELPER WAVES (wv 1..3), static EDF schedule =============
        const int w = wv - 1;
        const unsigned char* PT = (w == 0) ? PTAB0 : (w == 1) ? PTAB1 : PTAB2;
        const unsigned char* NT = (w == 0) ? NTOT0 : (w == 1) ? NTOT1 : NTOT2;
        const unsigned char* NM = (w == 0) ? NMAN0 : (w == 1) ? NMAN1 : NMAN2;
        int k = 0;
        for (int p = 0; p < 16; ++p) {
            const int nt = NT[p];
            const int nm = NM[p];
            // prefetch this iteration's pair bytes BEFORE the wait
            int q0 = 0, q1 = 0, q2 = 0;
            if (nt > 0) q0 = PT[k];
            if (nt > 1) q1 = PT[k + 1];
            if (nt > 2) q2 = PT[k + 2];
            k += nt;

            if (p >= 1) flag_wait(&flagI, p);   // chunks 0..p-1 published

            // ---- CRITICAL: mandatory pair (deadline == today), <=1 ----
            if (nm) DO_PAIR(q0);
            if (p < 15) flag_set(&flagH[wv], p + 1);   // targets <= p+1 final

            // ---- off-path: stores of chunk p-1 (fire-and-forget) ----
            if (p >= 1) {
                const int j = p * 64 - 64 + lane;
                if (wv == 1) {
                    const float s1 = Sh[j], i1 = Ih[j];
                    float* so = out + (size_t)j * (B_N * 3) + 3 * b;
                    so[0] = s1; so[1] = i1; so[2] = Rc - s1 - i1;
                } else if (wv == 2 && j >= 1) {
                    const float s1 = Sh[j], i1 = Ih[j];
                    const float s0 = Sh[j - 1], i0 = Ih[j - 1];
                    const float dS = (s1 - s0) * rdt;
                    const float dI = (i1 - i0) * rdt;
                    float* df = out + TB3 + (size_t)(j - 1) * (B_N * 3) + 3 * b;
                    df[0] = dS; df[1] = dI; df[2] = -(dS + dI);
                }
            }

            // ---- off-path: work-ahead pairs (<=3), release-safe by schedule ----
            if (nt - nm >= 1) { const int q = nm ? q1 : q0; DO_PAIR(q); }
            if (nt - nm >= 2) { const int q = nm ? q2 : q1; DO_PAIR(q); }
            if (nt - nm >= 3) { DO_PAIR(q2); }
        }
        // ---- epilogue: chunk 15 rows ----
        if (wv == 1 || wv == 2) {
            flag_wait(&flagI, 16);
            const int j = 960 + lane;
            if (wv == 1) {
                const float s1 = Sh[j], i1 = Ih[j];
                float* so = out + (size_t)j * (B_N * 3) + 3 * b;
                so[0] = s1; so[1] = i1; so[2] = Rc - s1 - i1;
            } else {
                const float s1 = Sh[j], i1 = Ih[j];
                const float s0 = Sh[j - 1], i0 = Ih[j - 1];
                const float dS = (s1 - s0) * rdt;
                const float dI = (i1 - i0) * rdt;
                float* df = out + TB3 + (size_t)(j - 1) * (B_N * 3) + 3 * b;
                df[0] = dS; df[1] = dI; df[2] = -(dS + dI);
            }
        }
    }
}

// ---------------- launcher ----------------
extern "C" void kernel_launch(void* const* d_in, const int* in_sizes, int n_in,
                              void* d_out, int out_size, void* d_ws, size_t ws_size,
                              hipStream_t stream)
{
    const float* t   = (const float*)d_in[0];
    const float* y   = (const float*)d_in[1];
    const float* w1  = (const float*)d_in[2];
    const float* b1  = (const float*)d_in[3];
    const float* w2  = (const float*)d_in[4];
    const float* b2  = (const float*)d_in[5];
    const float* w3  = (const float*)d_in[6];
    const float* b3  = (const float*)d_in[7];
    const float* w4  = (const float*)d_in[8];
    const float* b4  = (const float*)d_in[9];
    const float* bet = (const float*)d_in[10];
    const float* gam = (const float*)d_in[11];
    float* out = (float*)d_out;
    float* me  = (float*)d_ws;   // 1152 floats of scratch (me + zero pad)

    me_mlp_kernel<<<dim3(MEPAD / 64), dim3(64), 0, stream>>>(
        t, w1, b1, w2, b2, w3, b3, w4, b4, me);
    ode_kernel<<<dim3(B_N), dim3(256), 0, stream>>>(t, y, me, bet, gam, out);
}